// Round 1
// baseline (722.957 us; speedup 1.0000x reference)
//
#include <hip/hip_runtime.h>
#include <hip/hip_bf16.h>
#include <stdint.h>

// ---------------------------------------------------------------------------
// FMA-style hierarchical causal attention, MI355X (gfx950)
// B=4 T=8192 C=1024 H=16 D=64 M=64 P=8 L=6  -> BH=64, fine blocks nb0=128
// Pipeline: cast/transposeW -> GEMM1(qkv) -> transposeV -> poolK/poolV ->
//           fused attention -> GEMM2(proj)
// ---------------------------------------------------------------------------

typedef float  f32x4  __attribute__((ext_vector_type(4)));
typedef __bf16 bf16x8 __attribute__((ext_vector_type(8)));
typedef unsigned short ushort8 __attribute__((ext_vector_type(8)));

__device__ __forceinline__ unsigned short f2bf(float f) {
  union { float f; unsigned u; } v; v.f = f;
  unsigned r = v.u + 0x7fffu + ((v.u >> 16) & 1u);
  return (unsigned short)(r >> 16);
}
__device__ __forceinline__ float bf2f(unsigned short s) {
  union { unsigned u; float f; } v; v.u = ((unsigned)s) << 16;
  return v.f;
}
__device__ __forceinline__ bf16x8 ld_bf8(const unsigned short* p) {
  return __builtin_bit_cast(bf16x8, *(const ushort8*)p);
}
__device__ __forceinline__ f32x4 mfma16(bf16x8 a, bf16x8 b, f32x4 c) {
  return __builtin_amdgcn_mfma_f32_16x16x32_bf16(a, b, c, 0, 0, 0);
}
__device__ __forceinline__ f32x4 zero4() {
  f32x4 z; z[0] = 0.f; z[1] = 0.f; z[2] = 0.f; z[3] = 0.f; return z;
}
__device__ __forceinline__ void gload16(const void* g, void* lds) {
  __builtin_amdgcn_global_load_lds(
      (const __attribute__((address_space(1))) void*)(uintptr_t)g,
      (__attribute__((address_space(3))) void*)(unsigned int)(uintptr_t)lds,
      16, 0, 0);
}

#define T_SEQ 8192
#define NPOOL 2016   // 1024+512+256+128+64+32 pooled rows per bh

// --------------------------- cast x -> bf16 --------------------------------
__global__ __launch_bounds__(256) void castx_k(const float* __restrict__ x,
                                               unsigned short* __restrict__ xb) {
  size_t i = ((size_t)blockIdx.x * 256 + threadIdx.x) * 8;
  float4 a = *(const float4*)(x + i);
  float4 b = *(const float4*)(x + i + 4);
  ushort8 o;
  o[0] = f2bf(a.x); o[1] = f2bf(a.y); o[2] = f2bf(a.z); o[3] = f2bf(a.w);
  o[4] = f2bf(b.x); o[5] = f2bf(b.y); o[6] = f2bf(b.z); o[7] = f2bf(b.w);
  *(ushort8*)(xb + i) = o;
}

// ---------------- transpose W [R][C] f32 -> [C][R] bf16 --------------------
__global__ __launch_bounds__(256) void transposeW_k(const float* __restrict__ w,
                                                    unsigned short* __restrict__ wt,
                                                    int R, int C) {
  __shared__ float tile[64 * 65];
  int cc = blockIdx.x, rc = blockIdx.y;
  int tid = threadIdx.x;
#pragma unroll
  for (int p = 0; p < 4; ++p) {
    int ci = p * 256 + tid;
    int r = ci >> 4, q4 = ci & 15;
    float4 v = *(const float4*)(w + (size_t)(rc * 64 + r) * C + cc * 64 + q4 * 4);
    tile[r * 65 + q4 * 4 + 0] = v.x;
    tile[r * 65 + q4 * 4 + 1] = v.y;
    tile[r * 65 + q4 * 4 + 2] = v.z;
    tile[r * 65 + q4 * 4 + 3] = v.w;
  }
  __syncthreads();
#pragma unroll
  for (int p = 0; p < 2; ++p) {
    int orow = p * 32 + (tid >> 3), tg = tid & 7;
    ushort8 ov;
#pragma unroll
    for (int i = 0; i < 8; ++i) ov[i] = f2bf(tile[(tg * 8 + i) * 65 + orow]);
    *(ushort8*)(wt + (size_t)(cc * 64 + orow) * R + rc * 64 + tg * 8) = ov;
  }
}

// ---------------- GEMM1: qkv = x @ Wa + ba, scatter to q/k/v ---------------
// A [32768][1024] bf16 row-major, Bt [3072][1024] bf16 (= Wa^T)
__global__ __launch_bounds__(256) void gemm_qkv(const unsigned short* __restrict__ A,
                                                const unsigned short* __restrict__ Bt,
                                                const float* __restrict__ bias,
                                                unsigned short* __restrict__ qb,
                                                unsigned short* __restrict__ kb,
                                                unsigned short* __restrict__ vb) {
  const int K = 1024;
  __shared__ unsigned short As[128 * 32];
  __shared__ unsigned short Bs[128 * 32];
  int tm = blockIdx.x, tn = blockIdx.y;
  int tid = threadIdx.x;
  int w = tid >> 6, l = tid & 63;
  int wr = w >> 1, wc = w & 1;
  int lr = l & 15, lg = l >> 4;
  f32x4 acc[4][4];
#pragma unroll
  for (int i = 0; i < 4; ++i)
#pragma unroll
    for (int j = 0; j < 4; ++j) acc[i][j] = zero4();
  const size_t abase = (size_t)tm * 128 * K;
  const size_t bbase = (size_t)tn * 128 * K;
  for (int kt = 0; kt < K / 32; ++kt) {
#pragma unroll
    for (int p = 0; p < 2; ++p) {
      int c = tid + p * 256;
      int row = c >> 2, co = (c & 3) * 8;
      gload16(A + abase + (size_t)row * K + kt * 32 + co, &As[c * 8]);
      gload16(Bt + bbase + (size_t)row * K + kt * 32 + co, &Bs[c * 8]);
    }
    __syncthreads();
    bf16x8 af[4], bfr[4];
#pragma unroll
    for (int i = 0; i < 4; ++i) af[i] = ld_bf8(&As[(wr * 64 + i * 16 + lr) * 32 + lg * 8]);
#pragma unroll
    for (int j = 0; j < 4; ++j) bfr[j] = ld_bf8(&Bs[(wc * 64 + j * 16 + lr) * 32 + lg * 8]);
#pragma unroll
    for (int i = 0; i < 4; ++i)
#pragma unroll
      for (int j = 0; j < 4; ++j) acc[i][j] = mfma16(af[i], bfr[j], acc[i][j]);
    __syncthreads();
  }
  // epilogue: n<1024 -> q, <2048 -> k, else v ; layout [bh=b*16+h][t][d]
#pragma unroll
  for (int j = 0; j < 4; ++j) {
    int n = tn * 128 + wc * 64 + j * 16 + lr;
    float bv = bias[n];
    int region = n >> 10, nn = n & 1023, hh = nn >> 6, d = nn & 63;
    unsigned short* dst = region == 0 ? qb : (region == 1 ? kb : vb);
#pragma unroll
    for (int i = 0; i < 4; ++i) {
      int m0 = tm * 128 + wr * 64 + i * 16 + lg * 4;
#pragma unroll
      for (int e = 0; e < 4; ++e) {
        int m = m0 + e;
        int bb = m >> 13, t = m & 8191;
        dst[(((size_t)(bb * 16 + hh)) * T_SEQ + t) * 64 + d] = f2bf(acc[i][j][e] + bv);
      }
    }
  }
}

// ---------------- GEMM2: out = o @ Wp + bp (f32 out) -----------------------
__global__ __launch_bounds__(256) void gemm_proj(const unsigned short* __restrict__ A,
                                                 const unsigned short* __restrict__ Bt,
                                                 const float* __restrict__ bias,
                                                 float* __restrict__ out) {
  const int K = 1024;
  __shared__ unsigned short As[128 * 32];
  __shared__ unsigned short Bs[128 * 32];
  int tm = blockIdx.x, tn = blockIdx.y;
  int tid = threadIdx.x;
  int w = tid >> 6, l = tid & 63;
  int wr = w >> 1, wc = w & 1;
  int lr = l & 15, lg = l >> 4;
  f32x4 acc[4][4];
#pragma unroll
  for (int i = 0; i < 4; ++i)
#pragma unroll
    for (int j = 0; j < 4; ++j) acc[i][j] = zero4();
  const size_t abase = (size_t)tm * 128 * K;
  const size_t bbase = (size_t)tn * 128 * K;
  for (int kt = 0; kt < K / 32; ++kt) {
#pragma unroll
    for (int p = 0; p < 2; ++p) {
      int c = tid + p * 256;
      int row = c >> 2, co = (c & 3) * 8;
      gload16(A + abase + (size_t)row * K + kt * 32 + co, &As[c * 8]);
      gload16(Bt + bbase + (size_t)row * K + kt * 32 + co, &Bs[c * 8]);
    }
    __syncthreads();
    bf16x8 af[4], bfr[4];
#pragma unroll
    for (int i = 0; i < 4; ++i) af[i] = ld_bf8(&As[(wr * 64 + i * 16 + lr) * 32 + lg * 8]);
#pragma unroll
    for (int j = 0; j < 4; ++j) bfr[j] = ld_bf8(&Bs[(wc * 64 + j * 16 + lr) * 32 + lg * 8]);
#pragma unroll
    for (int i = 0; i < 4; ++i)
#pragma unroll
      for (int j = 0; j < 4; ++j) acc[i][j] = mfma16(af[i], bfr[j], acc[i][j]);
    __syncthreads();
  }
#pragma unroll
  for (int j = 0; j < 4; ++j) {
    int n = tn * 128 + wc * 64 + j * 16 + lr;
    float bv = bias[n];
#pragma unroll
    for (int i = 0; i < 4; ++i) {
      int m0 = tm * 128 + wr * 64 + i * 16 + lg * 4;
#pragma unroll
      for (int e = 0; e < 4; ++e) {
        int m = m0 + e;
        out[(size_t)m * 1024 + n] = acc[i][j][e] + bv;
      }
    }
  }
}

// ---------------- transpose v [bh][t][d] -> Vt [bh][d][t] ------------------
__global__ __launch_bounds__(256) void transposeV_k(const unsigned short* __restrict__ v,
                                                    unsigned short* __restrict__ vt) {
  __shared__ float tile[64 * 65];
  int tc = blockIdx.x, bh = blockIdx.y;
  int tid = threadIdx.x;
#pragma unroll
  for (int p = 0; p < 2; ++p) {
    int r = p * 32 + (tid >> 3), cg = tid & 7;
    ushort8 u = *(const ushort8*)(v + ((size_t)bh * T_SEQ + (size_t)tc * 64 + r) * 64 + cg * 8);
#pragma unroll
    for (int i = 0; i < 8; ++i) tile[r * 65 + cg * 8 + i] = bf2f(u[i]);
  }
  __syncthreads();
#pragma unroll
  for (int p = 0; p < 2; ++p) {
    int dd = p * 32 + (tid >> 3), tg = tid & 7;
    ushort8 ov;
#pragma unroll
    for (int i = 0; i < 8; ++i) ov[i] = f2bf(tile[(tg * 8 + i) * 65 + dd]);
    *(ushort8*)(vt + ((size_t)bh * 64 + dd) * T_SEQ + (size_t)tc * 64 + tg * 8) = ov;
  }
}

// ---------------- pool K: k [bh][t][d] -> kpool [bh][2016][d] --------------
// level l (1..6): pool r=8*2^(l-1); offsets 0,1024,1536,1792,1920,1984
__global__ __launch_bounds__(256) void poolK_k(const unsigned short* __restrict__ kin,
                                               unsigned short* __restrict__ kpool) {
  __shared__ float buf[64 * 65];
  int chunk = blockIdx.x, bh = blockIdx.y;  // chunk of 256 t-rows
  int tid = threadIdx.x;
  int cg = tid & 7, orow = tid >> 3;  // orow 0..31 (level-1 rows in chunk)
  float s[8];
#pragma unroll
  for (int i = 0; i < 8; ++i) s[i] = 0.f;
  const unsigned short* base =
      kin + ((size_t)bh * T_SEQ + chunk * 256 + orow * 8) * 64 + cg * 8;
#pragma unroll
  for (int rr = 0; rr < 8; ++rr) {
    ushort8 v = *(const ushort8*)(base + (size_t)rr * 64);
#pragma unroll
    for (int i = 0; i < 8; ++i) s[i] += bf2f(v[i]);
  }
  unsigned short* kp = kpool + (size_t)bh * NPOOL * 64;
  {
    ushort8 ov;
#pragma unroll
    for (int i = 0; i < 8; ++i) {
      s[i] *= 0.125f;
      ov[i] = f2bf(s[i]);
      buf[orow * 65 + cg * 8 + i] = s[i];
    }
    *(ushort8*)(kp + ((size_t)(chunk * 32 + orow)) * 64 + cg * 8) = ov;
  }
  __syncthreads();
  int srcR = 0, dstR = 32;
#pragma unroll
  for (int lvl = 2; lvl <= 6; ++lvl) {
    int rows = 32 >> (lvl - 1);             // 16,8,4,2,1
    int off = 2048 - (2048 >> (lvl - 1));   // 1024,1536,1792,1920,1984
    if (orow < rows) {
      ushort8 ov;
      float tv[8];
#pragma unroll
      for (int i = 0; i < 8; ++i) {
        tv[i] = 0.5f * (buf[(srcR + 2 * orow) * 65 + cg * 8 + i] +
                        buf[(srcR + 2 * orow + 1) * 65 + cg * 8 + i]);
        ov[i] = f2bf(tv[i]);
      }
      *(ushort8*)(kp + ((size_t)(off + chunk * rows + orow)) * 64 + cg * 8) = ov;
#pragma unroll
      for (int i = 0; i < 8; ++i) buf[(dstR + orow) * 65 + cg * 8 + i] = tv[i];
    }
    __syncthreads();
    srcR = dstR;
    dstR += rows;
  }
}

// ---------------- pool V (transposed space): Vt -> Vtpool ------------------
__global__ __launch_bounds__(256) void poolV_k(const unsigned short* __restrict__ vt,
                                               unsigned short* __restrict__ vtpool) {
  __shared__ float buf[1024 + 512 + 256 + 128 + 64];
  int d = blockIdx.x, bh = blockIdx.y;
  int tid = threadIdx.x;
  const unsigned short* src = vt + ((size_t)bh * 64 + d) * T_SEQ;
  unsigned short* dst = vtpool + ((size_t)bh * 64 + d) * NPOOL;
#pragma unroll
  for (int p = 0; p < 4; ++p) {
    int oi = p * 256 + tid;
    ushort8 v = *(const ushort8*)(src + (size_t)oi * 8);
    float s = 0.f;
#pragma unroll
    for (int i = 0; i < 8; ++i) s += bf2f(v[i]);
    s *= 0.125f;
    dst[oi] = f2bf(s);
    buf[oi] = s;
  }
  __syncthreads();
  float* b1 = buf; float* b2 = buf + 1024;
#pragma unroll
  for (int p = 0; p < 2; ++p) {
    int oi = p * 256 + tid;
    float s = 0.5f * (b1[2 * oi] + b1[2 * oi + 1]);
    dst[1024 + oi] = f2bf(s);
    b2[oi] = s;
  }
  __syncthreads();
  float* b3 = b2 + 512;
  {
    float s = 0.5f * (b2[2 * tid] + b2[2 * tid + 1]);
    dst[1536 + tid] = f2bf(s);
    b3[tid] = s;
  }
  __syncthreads();
  float* b4 = b3 + 256;
  if (tid < 128) {
    float s = 0.5f * (b3[2 * tid] + b3[2 * tid + 1]);
    dst[1792 + tid] = f2bf(s);
    b4[tid] = s;
  }
  __syncthreads();
  float* b5 = b4 + 128;
  if (tid < 64) {
    float s = 0.5f * (b4[2 * tid] + b4[2 * tid + 1]);
    dst[1920 + tid] = f2bf(s);
    b5[tid] = s;
  }
  __syncthreads();
  if (tid < 32) {
    float s = 0.5f * (b5[2 * tid] + b5[2 * tid + 1]);
    dst[1984 + tid] = f2bf(s);
  }
}

// ---------------- fused hierarchical attention -----------------------------
// block = (fine block g of 64 q-rows, bh). 224 keys: 128 fine + 6*16 pooled.
__global__ __launch_bounds__(256) void attn_k(const unsigned short* __restrict__ q,
                                              const unsigned short* __restrict__ k,
                                              const unsigned short* __restrict__ kpool,
                                              const unsigned short* __restrict__ vt,
                                              const unsigned short* __restrict__ vtpool,
                                              unsigned short* __restrict__ o) {
  const int g = blockIdx.x;   // 0..127
  const int bh = blockIdx.y;  // 0..63
  const int tid = threadIdx.x;
  const int w = tid >> 6, l = tid & 63;
  const int lr = l & 15, lg = l >> 4;
  __shared__ unsigned short Pl[64 * 232];

  // Q A-frags (rows g*64 + w*16 + lr)
  const size_t qoff = ((size_t)bh * T_SEQ + (size_t)g * 64 + w * 16 + lr) * 64 + lg * 8;
  bf16x8 aq0 = ld_bf8(q + qoff);
  bf16x8 aq1 = ld_bf8(q + qoff + 32);

  f32x4 S[14];
#pragma unroll
  for (int ct = 0; ct < 14; ++ct) S[ct] = zero4();

  // fine keys: col c = ct*16+lr -> t = (g-1)*64 + c
#pragma unroll
  for (int ct = 0; ct < 8; ++ct) {
    int t = (g - 1) * 64 + ct * 16 + lr;
    int tc = t < 0 ? 0 : t;
    const unsigned short* kr = k + ((size_t)bh * T_SEQ + tc) * 64 + lg * 8;
    S[ct] = mfma16(aq0, ld_bf8(kr), S[ct]);
    S[ct] = mfma16(aq1, ld_bf8(kr + 32), S[ct]);
  }
  // coarse levels 1..6: 16 cols each (j<8: block gl-2, j>=8: gl-1)
#pragma unroll
  for (int lvl = 1; lvl <= 6; ++lvl) {
    int ct = 7 + lvl;
    int gl = g >> (lvl - 1);
    int off = 2048 - (2048 >> (lvl - 1));
    int prow = (gl - 2) * 8 + lr;
    int prc = prow < 0 ? 0 : prow;
    const unsigned short* kr = kpool + ((size_t)bh * NPOOL + off + prc) * 64 + lg * 8;
    S[ct] = mfma16(aq0, ld_bf8(kr), S[ct]);
    S[ct] = mfma16(aq1, ld_bf8(kr + 32), S[ct]);
  }

  // mask + scale 1/sqrt(64)
  const float NEGF = -1e30f;
#pragma unroll
  for (int ct = 0; ct < 14; ++ct) {
#pragma unroll
    for (int e = 0; e < 4; ++e) {
      int r = w * 16 + lg * 4 + e;
      float s = S[ct][e] * 0.125f;
      bool valid;
      if (ct < 8) {
        int c = ct * 16 + lr;
        valid = (c > r) && (c <= r + 64) && ((g >= 1) || (c >= 64));
      } else {
        int lvl = ct - 7;
        int gl = g >> (lvl - 1);
        valid = gl >= ((lr < 8) ? 2 : 1);
      }
      S[ct][e] = valid ? s : NEGF;
    }
  }
  // shared max + scaled denom (scales: fine=1, level l = 8*2^(l-1))
  float mrow[4], invd[4];
#pragma unroll
  for (int e = 0; e < 4; ++e) {
    float mx = S[0][e];
#pragma unroll
    for (int ct = 1; ct < 14; ++ct) mx = fmaxf(mx, S[ct][e]);
    mx = fmaxf(mx, __shfl_xor(mx, 1));
    mx = fmaxf(mx, __shfl_xor(mx, 2));
    mx = fmaxf(mx, __shfl_xor(mx, 4));
    mx = fmaxf(mx, __shfl_xor(mx, 8));
    mrow[e] = mx;
  }
#pragma unroll
  for (int e = 0; e < 4; ++e) {
    float sum = 0.f;
#pragma unroll
    for (int ct = 0; ct < 14; ++ct) {
      float sc = (ct < 8) ? 1.0f : (float)(8 << (ct - 8));
      float ev = sc * __expf(S[ct][e] - mrow[e]);
      S[ct][e] = ev;
      sum += ev;
    }
    sum += __shfl_xor(sum, 1);
    sum += __shfl_xor(sum, 2);
    sum += __shfl_xor(sum, 4);
    sum += __shfl_xor(sum, 8);
    invd[e] = 1.0f / sum;
  }
  // P -> LDS bf16 (row stride 232 keeps 16B-aligned rows)
#pragma unroll
  for (int ct = 0; ct < 14; ++ct) {
#pragma unroll
    for (int e = 0; e < 4; ++e) {
      int r = w * 16 + lg * 4 + e;
      Pl[r * 232 + ct * 16 + lr] = f2bf(S[ct][e] * invd[e]);
    }
  }
  __syncthreads();

  // PV: out[64][64] = P[64][224] @ Vcat[224][64], B-frags from global Vt
  f32x4 O[4];
#pragma unroll
  for (int c2 = 0; c2 < 4; ++c2) O[c2] = zero4();
#pragma unroll
  for (int kc = 0; kc < 7; ++kc) {
    bf16x8 pa = ld_bf8(&Pl[(w * 16 + lr) * 232 + kc * 32 + lg * 8]);
    int kk = kc * 32 + lg * 8;
#pragma unroll
    for (int c2 = 0; c2 < 4; ++c2) {
      int d = c2 * 16 + lr;
      const unsigned short* vr;
      if (kk < 128) {
        int t = (g - 1) * 64 + kk;
        int tc = t < 0 ? 0 : t;
        vr = vt + ((size_t)bh * 64 + d) * T_SEQ + tc;
      } else {
        int idx = kk - 128;
        int lvl0 = idx >> 4;  // 0..5 == level-1
        int j = idx & 15;
        int gl = g >> lvl0;
        int off = 2048 - (2048 >> lvl0);
        int prow = (gl - 2) * 8 + j;
        int prc = prow < 0 ? 0 : prow;
        vr = vtpool + ((size_t)bh * 64 + d) * NPOOL + off + prc;
      }
      O[c2] = mfma16(pa, ld_bf8(vr), O[c2]);
    }
  }
  // write o as [b][t][h*64+d] (row-major [32768][1024])
  const int bb = bh >> 4, hh = bh & 15;
#pragma unroll
  for (int c2 = 0; c2 < 4; ++c2) {
    int d = c2 * 16 + lr;
#pragma unroll
    for (int e = 0; e < 4; ++e) {
      int t = g * 64 + w * 16 + lg * 4 + e;
      o[((size_t)bb * T_SEQ + t) * 1024 + hh * 64 + d] = f2bf(O[c2][e]);
    }
  }
}

// ---------------------------------------------------------------------------
extern "C" void kernel_launch(void* const* d_in, const int* in_sizes, int n_in,
                              void* d_out, int out_size, void* d_ws, size_t ws_size,
                              hipStream_t stream) {
  const float* x  = (const float*)d_in[0];
  const float* Wa = (const float*)d_in[1];
  const float* ba = (const float*)d_in[2];
  const float* Wp = (const float*)d_in[3];
  const float* bp = (const float*)d_in[4];
  float* out = (float*)d_out;
  char* ws = (char*)d_ws;
  const size_t MB = 1024 * 1024;

  unsigned short* xb  = (unsigned short*)(ws);             // 64MB (dead after GEMM1)
  unsigned short* qb  = (unsigned short*)(ws + 64 * MB);   // 64MB
  unsigned short* kb  = (unsigned short*)(ws + 128 * MB);  // 64MB
  unsigned short* vb  = (unsigned short*)(ws + 192 * MB);  // 64MB (-> o after transpose)
  unsigned short* vt  = (unsigned short*)(ws + 256 * MB);  // 64MB
  unsigned short* wat = (unsigned short*)(ws + 320 * MB);  // 6MB
  unsigned short* wpt = (unsigned short*)(ws + 326 * MB);  // 2MB
  unsigned short* kpool  = xb;                             // 15.75MB (aliases xb)
  unsigned short* vtpool = (unsigned short*)(ws + 32 * MB);// 15.75MB (aliases xb)

  castx_k<<<16384, 256, 0, stream>>>(x, xb);
  transposeW_k<<<dim3(48, 16), 256, 0, stream>>>(Wa, wat, 1024, 3072);
  transposeW_k<<<dim3(16, 16), 256, 0, stream>>>(Wp, wpt, 1024, 1024);
  gemm_qkv<<<dim3(256, 24), 256, 0, stream>>>(xb, wat, ba, qb, kb, vb);
  transposeV_k<<<dim3(128, 64), 256, 0, stream>>>(vb, vt);
  poolK_k<<<dim3(32, 64), 256, 0, stream>>>(kb, kpool);
  poolV_k<<<dim3(64, 64), 256, 0, stream>>>(vt, vtpool);
  attn_k<<<dim3(128, 64), 256, 0, stream>>>(qb, kb, kpool, vt, vtpool, vb);
  gemm_proj<<<dim3(256, 8), 256, 0, stream>>>(vb, wpt, bp, out);
}

// Round 2
// 643.716 us; speedup vs baseline: 1.1231x; 1.1231x over previous
//
#include <hip/hip_runtime.h>
#include <hip/hip_bf16.h>
#include <stdint.h>

// ---------------------------------------------------------------------------
// FMA-style hierarchical causal attention, MI355X (gfx950)
// B=4 T=8192 C=1024 H=16 D=64 M=64 P=8 L=6  -> BH=64, fine blocks nb0=128
// R1: 256^2 BK=64 counted-vmcnt pipelined GEMMs (T1+T2+T4+T5), race-free
//     stage-after-compute schedule with vmcnt(8).
// ---------------------------------------------------------------------------

typedef float  f32x4  __attribute__((ext_vector_type(4)));
typedef __bf16 bf16x8 __attribute__((ext_vector_type(8)));
typedef unsigned short ushort8 __attribute__((ext_vector_type(8)));

__device__ __forceinline__ unsigned short f2bf(float f) {
  union { float f; unsigned u; } v; v.f = f;
  unsigned r = v.u + 0x7fffu + ((v.u >> 16) & 1u);
  return (unsigned short)(r >> 16);
}
__device__ __forceinline__ float bf2f(unsigned short s) {
  union { unsigned u; float f; } v; v.u = ((unsigned)s) << 16;
  return v.f;
}
__device__ __forceinline__ bf16x8 ld_bf8(const unsigned short* p) {
  return __builtin_bit_cast(bf16x8, *(const ushort8*)p);
}
__device__ __forceinline__ f32x4 mfma16(bf16x8 a, bf16x8 b, f32x4 c) {
  return __builtin_amdgcn_mfma_f32_16x16x32_bf16(a, b, c, 0, 0, 0);
}
__device__ __forceinline__ f32x4 zero4() {
  f32x4 z; z[0] = 0.f; z[1] = 0.f; z[2] = 0.f; z[3] = 0.f; return z;
}
__device__ __forceinline__ void gload16(const void* g, void* lds) {
  __builtin_amdgcn_global_load_lds(
      (const __attribute__((address_space(1))) void*)(uintptr_t)g,
      (__attribute__((address_space(3))) void*)(unsigned int)(uintptr_t)lds,
      16, 0, 0);
}

#define T_SEQ 8192
#define NPOOL 2016   // 1024+512+256+128+64+32 pooled rows per bh

// --------------------------- cast x -> bf16 --------------------------------
__global__ __launch_bounds__(256) void castx_k(const float* __restrict__ x,
                                               unsigned short* __restrict__ xb) {
  size_t i = ((size_t)blockIdx.x * 256 + threadIdx.x) * 8;
  float4 a = *(const float4*)(x + i);
  float4 b = *(const float4*)(x + i + 4);
  ushort8 o;
  o[0] = f2bf(a.x); o[1] = f2bf(a.y); o[2] = f2bf(a.z); o[3] = f2bf(a.w);
  o[4] = f2bf(b.x); o[5] = f2bf(b.y); o[6] = f2bf(b.z); o[7] = f2bf(b.w);
  *(ushort8*)(xb + i) = o;
}

// ---------------- transpose W [R][C] f32 -> [C][R] bf16 --------------------
__global__ __launch_bounds__(256) void transposeW_k(const float* __restrict__ w,
                                                    unsigned short* __restrict__ wt,
                                                    int R, int C) {
  __shared__ float tile[64 * 65];
  int cc = blockIdx.x, rc = blockIdx.y;
  int tid = threadIdx.x;
#pragma unroll
  for (int p = 0; p < 4; ++p) {
    int ci = p * 256 + tid;
    int r = ci >> 4, q4 = ci & 15;
    float4 v = *(const float4*)(w + (size_t)(rc * 64 + r) * C + cc * 64 + q4 * 4);
    tile[r * 65 + q4 * 4 + 0] = v.x;
    tile[r * 65 + q4 * 4 + 1] = v.y;
    tile[r * 65 + q4 * 4 + 2] = v.z;
    tile[r * 65 + q4 * 4 + 3] = v.w;
  }
  __syncthreads();
#pragma unroll
  for (int p = 0; p < 2; ++p) {
    int orow = p * 32 + (tid >> 3), tg = tid & 7;
    ushort8 ov;
#pragma unroll
    for (int i = 0; i < 8; ++i) ov[i] = f2bf(tile[(tg * 8 + i) * 65 + orow]);
    *(ushort8*)(wt + (size_t)(cc * 64 + orow) * R + rc * 64 + tg * 8) = ov;
  }
}

// ---------------------------------------------------------------------------
// 256x256 BK=64 pipelined GEMM. A [M][1024] bf16 rm, Bt [N][1024] bf16 (B^T).
// 512 thr = 8 waves (2 wm x 4 wn), per-wave out 128x64 (acc[8][4]).
// LDS 128KB: 2 bufs x (A 32KB + B 32KB); half-tile = 128 rows x 64 cols.
// 16B-seg XOR swizzle: slot(r,p) holds colseg p^(r&7) (pre-swizzled source).
// Pipeline: stage t+2 after end-of-tile barrier, vmcnt(8) keeps only the 8
// just-issued loads in flight -> tile t+1 resident at swap barrier.
// EPI 0: scatter qkv + bias -> [bh][t][d]; EPI 1: f32 out[m][n] + bias.
// ---------------------------------------------------------------------------
template<int NTILE_N, int EPI>
__global__ __launch_bounds__(512, 2) void gemm256(
    const unsigned short* __restrict__ A, const unsigned short* __restrict__ Bt,
    const float* __restrict__ bias,
    unsigned short* __restrict__ o0, unsigned short* __restrict__ o1,
    unsigned short* __restrict__ o2, float* __restrict__ fout) {
  extern __shared__ __align__(16) char smem[];
  const int K = 1024;
  const int nwg = 128 * NTILE_N;
  const int q = nwg >> 3;
  const int wg = ((int)blockIdx.x & 7) * q + ((int)blockIdx.x >> 3);  // XCD swizzle
  const int tm = wg & 127, tn = wg >> 7;
  const int tid = threadIdx.x;
  const int wid = tid >> 6, lane = tid & 63;
  const int wm = wid >> 2, wn = wid & 3;
  const int lr = lane & 15, lg = lane >> 4;

  // staging decomposition: thread covers rows r, r+64 (x2 halves), seg c
  const int r = tid >> 3;
  const int c = (tid & 7) ^ (r & 7);
  const unsigned short* aP = A + (size_t)(tm * 256 + r) * K + c * 8;
  const unsigned short* bP = Bt + (size_t)(tn * 256 + r) * K + c * 8;

  // fragment read bases (phys seg = ((kh<<2)|lg) ^ (lr&7); row low bits = lr&7)
  const int ps0 = ((lg) ^ (lr & 7)) * 16;
  const int ps1 = ((4 | lg) ^ (lr & 7)) * 16;
  const unsigned aRB = (unsigned)(wm * 16384 + lr * 128);
  const unsigned bRB = (unsigned)(32768 + (wn >> 1) * 16384 + (wn & 1) * 8192 + lr * 128);

  f32x4 acc[8][4];
#pragma unroll
  for (int i = 0; i < 8; ++i)
#pragma unroll
    for (int j = 0; j < 4; ++j) acc[i][j] = zero4();

  auto stage = [&](int kt, unsigned bufB) {
#pragma unroll
    for (int h = 0; h < 2; ++h)
#pragma unroll
      for (int j = 0; j < 2; ++j) {
        const size_t rowoff = (size_t)(h * 128 + j * 64) * K + (size_t)kt * 64;
        const unsigned ldso = bufB + (unsigned)(h * 16384 + (j * 512 + tid) * 16);
        gload16(aP + rowoff, smem + ldso);
        gload16(bP + rowoff, smem + 32768 + ldso);
      }
  };

  auto computeTile = [&](unsigned bufB) {
    const char* base = smem + bufB;
    bf16x8 rB[4][2], rA[4][2];
#pragma unroll
    for (int j = 0; j < 4; ++j) {
      rB[j][0] = ld_bf8((const unsigned short*)(base + bRB + j * 2048 + ps0));
      rB[j][1] = ld_bf8((const unsigned short*)(base + bRB + j * 2048 + ps1));
    }
#pragma unroll
    for (int i = 0; i < 4; ++i) {
      rA[i][0] = ld_bf8((const unsigned short*)(base + aRB + i * 2048 + ps0));
      rA[i][1] = ld_bf8((const unsigned short*)(base + aRB + i * 2048 + ps1));
    }
    __builtin_amdgcn_sched_barrier(0);
    __builtin_amdgcn_s_barrier();
    asm volatile("s_waitcnt lgkmcnt(0)" ::: "memory");
    __builtin_amdgcn_sched_barrier(0);
    __builtin_amdgcn_s_setprio(1);
#pragma unroll
    for (int i = 0; i < 4; ++i)
#pragma unroll
      for (int j = 0; j < 4; ++j) {
        acc[i][j] = mfma16(rA[i][0], rB[j][0], acc[i][j]);
        acc[i][j] = mfma16(rA[i][1], rB[j][1], acc[i][j]);
      }
    __builtin_amdgcn_s_setprio(0);
    __builtin_amdgcn_sched_barrier(0);
    // phase beta: reread A rows i=4..7 (read-read overlap, no barrier hazard)
    bf16x8 rC[4][2];
#pragma unroll
    for (int i = 0; i < 4; ++i) {
      rC[i][0] = ld_bf8((const unsigned short*)(base + aRB + (i + 4) * 2048 + ps0));
      rC[i][1] = ld_bf8((const unsigned short*)(base + aRB + (i + 4) * 2048 + ps1));
    }
    __builtin_amdgcn_sched_barrier(0);
    __builtin_amdgcn_s_barrier();
    asm volatile("s_waitcnt lgkmcnt(0)" ::: "memory");
    __builtin_amdgcn_sched_barrier(0);
    __builtin_amdgcn_s_setprio(1);
#pragma unroll
    for (int i = 0; i < 4; ++i)
#pragma unroll
      for (int j = 0; j < 4; ++j) {
        acc[i + 4][j] = mfma16(rC[i][0], rB[j][0], acc[i + 4][j]);
        acc[i + 4][j] = mfma16(rC[i][1], rB[j][1], acc[i + 4][j]);
      }
    __builtin_amdgcn_s_setprio(0);
    __builtin_amdgcn_sched_barrier(0);
    __builtin_amdgcn_s_barrier();  // end-of-tile: all waves done reading bufB
  };

  stage(0, 0);
  stage(1, 65536);
  asm volatile("s_waitcnt vmcnt(8)" ::: "memory");
  __builtin_amdgcn_sched_barrier(0);
  __builtin_amdgcn_s_barrier();

  for (int t = 0; t < 16; ++t) {
    const unsigned bufB = (unsigned)(t & 1) * 65536u;
    computeTile(bufB);
    if (t < 14) {
      stage(t + 2, bufB);
      asm volatile("s_waitcnt vmcnt(8)" ::: "memory");
      __builtin_amdgcn_sched_barrier(0);
      __builtin_amdgcn_s_barrier();
    } else if (t == 14) {
      asm volatile("s_waitcnt vmcnt(0)" ::: "memory");
      __builtin_amdgcn_sched_barrier(0);
      __builtin_amdgcn_s_barrier();
    }
  }

  const int mBase = tm * 256 + wm * 128 + lg * 4;
  const int nBase = tn * 256 + wn * 64 + lr;
  if (EPI == 0) {
#pragma unroll
    for (int j = 0; j < 4; ++j) {
      int n = nBase + j * 16;
      float bv = bias[n];
      int region = n >> 10, nn = n & 1023, hh = nn >> 6, d = nn & 63;
      unsigned short* dst = region == 0 ? o0 : (region == 1 ? o1 : o2);
#pragma unroll
      for (int i = 0; i < 8; ++i) {
#pragma unroll
        for (int e = 0; e < 4; ++e) {
          int m = mBase + i * 16 + e;
          int bb = m >> 13, tq = m & 8191;
          dst[(((size_t)(bb * 16 + hh)) * T_SEQ + tq) * 64 + d] = f2bf(acc[i][j][e] + bv);
        }
      }
    }
  } else {
#pragma unroll
    for (int j = 0; j < 4; ++j) {
      int n = nBase + j * 16;
      float bv = bias[n];
#pragma unroll
      for (int i = 0; i < 8; ++i) {
#pragma unroll
        for (int e = 0; e < 4; ++e) {
          int m = mBase + i * 16 + e;
          fout[(size_t)m * 1024 + n] = acc[i][j][e] + bv;
        }
      }
    }
  }
}

// ---------------- transpose v [bh][t][d] -> Vt [bh][d][t] ------------------
__global__ __launch_bounds__(256) void transposeV_k(const unsigned short* __restrict__ v,
                                                    unsigned short* __restrict__ vt) {
  __shared__ float tile[64 * 65];
  int tc = blockIdx.x, bh = blockIdx.y;
  int tid = threadIdx.x;
#pragma unroll
  for (int p = 0; p < 2; ++p) {
    int r = p * 32 + (tid >> 3), cg = tid & 7;
    ushort8 u = *(const ushort8*)(v + ((size_t)bh * T_SEQ + (size_t)tc * 64 + r) * 64 + cg * 8);
#pragma unroll
    for (int i = 0; i < 8; ++i) tile[r * 65 + cg * 8 + i] = bf2f(u[i]);
  }
  __syncthreads();
#pragma unroll
  for (int p = 0; p < 2; ++p) {
    int dd = p * 32 + (tid >> 3), tg = tid & 7;
    ushort8 ov;
#pragma unroll
    for (int i = 0; i < 8; ++i) ov[i] = f2bf(tile[(tg * 8 + i) * 65 + dd]);
    *(ushort8*)(vt + ((size_t)bh * 64 + dd) * T_SEQ + (size_t)tc * 64 + tg * 8) = ov;
  }
}

// ---------------- pool K: k [bh][t][d] -> kpool [bh][2016][d] --------------
__global__ __launch_bounds__(256) void poolK_k(const unsigned short* __restrict__ kin,
                                               unsigned short* __restrict__ kpool) {
  __shared__ float buf[64 * 65];
  int chunk = blockIdx.x, bh = blockIdx.y;
  int tid = threadIdx.x;
  int cg = tid & 7, orow = tid >> 3;
  float s[8];
#pragma unroll
  for (int i = 0; i < 8; ++i) s[i] = 0.f;
  const unsigned short* base =
      kin + ((size_t)bh * T_SEQ + chunk * 256 + orow * 8) * 64 + cg * 8;
#pragma unroll
  for (int rr = 0; rr < 8; ++rr) {
    ushort8 v = *(const ushort8*)(base + (size_t)rr * 64);
#pragma unroll
    for (int i = 0; i < 8; ++i) s[i] += bf2f(v[i]);
  }
  unsigned short* kp = kpool + (size_t)bh * NPOOL * 64;
  {
    ushort8 ov;
#pragma unroll
    for (int i = 0; i < 8; ++i) {
      s[i] *= 0.125f;
      ov[i] = f2bf(s[i]);
      buf[orow * 65 + cg * 8 + i] = s[i];
    }
    *(ushort8*)(kp + ((size_t)(chunk * 32 + orow)) * 64 + cg * 8) = ov;
  }
  __syncthreads();
  int srcR = 0, dstR = 32;
#pragma unroll
  for (int lvl = 2; lvl <= 6; ++lvl) {
    int rows = 32 >> (lvl - 1);
    int off = 2048 - (2048 >> (lvl - 1));
    if (orow < rows) {
      ushort8 ov;
      float tv[8];
#pragma unroll
      for (int i = 0; i < 8; ++i) {
        tv[i] = 0.5f * (buf[(srcR + 2 * orow) * 65 + cg * 8 + i] +
                        buf[(srcR + 2 * orow + 1) * 65 + cg * 8 + i]);
        ov[i] = f2bf(tv[i]);
      }
      *(ushort8*)(kp + ((size_t)(off + chunk * rows + orow)) * 64 + cg * 8) = ov;
#pragma unroll
      for (int i = 0; i < 8; ++i) buf[(dstR + orow) * 65 + cg * 8 + i] = tv[i];
    }
    __syncthreads();
    srcR = dstR;
    dstR += rows;
  }
}

// ---------------- pool V (transposed space): Vt -> Vtpool ------------------
__global__ __launch_bounds__(256) void poolV_k(const unsigned short* __restrict__ vt,
                                               unsigned short* __restrict__ vtpool) {
  __shared__ float buf[1024 + 512 + 256 + 128 + 64];
  int d = blockIdx.x, bh = blockIdx.y;
  int tid = threadIdx.x;
  const unsigned short* src = vt + ((size_t)bh * 64 + d) * T_SEQ;
  unsigned short* dst = vtpool + ((size_t)bh * 64 + d) * NPOOL;
#pragma unroll
  for (int p = 0; p < 4; ++p) {
    int oi = p * 256 + tid;
    ushort8 v = *(const ushort8*)(src + (size_t)oi * 8);
    float s = 0.f;
#pragma unroll
    for (int i = 0; i < 8; ++i) s += bf2f(v[i]);
    s *= 0.125f;
    dst[oi] = f2bf(s);
    buf[oi] = s;
  }
  __syncthreads();
  float* b1 = buf; float* b2 = buf + 1024;
#pragma unroll
  for (int p = 0; p < 2; ++p) {
    int oi = p * 256 + tid;
    float s = 0.5f * (b1[2 * oi] + b1[2 * oi + 1]);
    dst[1024 + oi] = f2bf(s);
    b2[oi] = s;
  }
  __syncthreads();
  float* b3 = b2 + 512;
  {
    float s = 0.5f * (b2[2 * tid] + b2[2 * tid + 1]);
    dst[1536 + tid] = f2bf(s);
    b3[tid] = s;
  }
  __syncthreads();
  float* b4 = b3 + 256;
  if (tid < 128) {
    float s = 0.5f * (b3[2 * tid] + b3[2 * tid + 1]);
    dst[1792 + tid] = f2bf(s);
    b4[tid] = s;
  }
  __syncthreads();
  float* b5 = b4 + 128;
  if (tid < 64) {
    float s = 0.5f * (b4[2 * tid] + b4[2 * tid + 1]);
    dst[1920 + tid] = f2bf(s);
    b5[tid] = s;
  }
  __syncthreads();
  if (tid < 32) {
    float s = 0.5f * (b5[2 * tid] + b5[2 * tid + 1]);
    dst[1984 + tid] = f2bf(s);
  }
}

// ---------------- fused hierarchical attention -----------------------------
__global__ __launch_bounds__(256) void attn_k(const unsigned short* __restrict__ q,
                                              const unsigned short* __restrict__ k,
                                              const unsigned short* __restrict__ kpool,
                                              const unsigned short* __restrict__ vt,
                                              const unsigned short* __restrict__ vtpool,
                                              unsigned short* __restrict__ o) {
  const int g = blockIdx.x;
  const int bh = blockIdx.y;
  const int tid = threadIdx.x;
  const int w = tid >> 6, l = tid & 63;
  const int lr = l & 15, lg = l >> 4;
  __shared__ unsigned short Pl[64 * 232];

  const size_t qoff = ((size_t)bh * T_SEQ + (size_t)g * 64 + w * 16 + lr) * 64 + lg * 8;
  bf16x8 aq0 = ld_bf8(q + qoff);
  bf16x8 aq1 = ld_bf8(q + qoff + 32);

  f32x4 S[14];
#pragma unroll
  for (int ct = 0; ct < 14; ++ct) S[ct] = zero4();

#pragma unroll
  for (int ct = 0; ct < 8; ++ct) {
    int t = (g - 1) * 64 + ct * 16 + lr;
    int tc = t < 0 ? 0 : t;
    const unsigned short* kr = k + ((size_t)bh * T_SEQ + tc) * 64 + lg * 8;
    S[ct] = mfma16(aq0, ld_bf8(kr), S[ct]);
    S[ct] = mfma16(aq1, ld_bf8(kr + 32), S[ct]);
  }
#pragma unroll
  for (int lvl = 1; lvl <= 6; ++lvl) {
    int ct = 7 + lvl;
    int gl = g >> (lvl - 1);
    int off = 2048 - (2048 >> (lvl - 1));
    int prow = (gl - 2) * 8 + lr;
    int prc = prow < 0 ? 0 : prow;
    const unsigned short* kr = kpool + ((size_t)bh * NPOOL + off + prc) * 64 + lg * 8;
    S[ct] = mfma16(aq0, ld_bf8(kr), S[ct]);
    S[ct] = mfma16(aq1, ld_bf8(kr + 32), S[ct]);
  }

  const float NEGF = -1e30f;
#pragma unroll
  for (int ct = 0; ct < 14; ++ct) {
#pragma unroll
    for (int e = 0; e < 4; ++e) {
      int rr = w * 16 + lg * 4 + e;
      float s = S[ct][e] * 0.125f;
      bool valid;
      if (ct < 8) {
        int cc = ct * 16 + lr;
        valid = (cc > rr) && (cc <= rr + 64) && ((g >= 1) || (cc >= 64));
      } else {
        int lvl = ct - 7;
        int gl = g >> (lvl - 1);
        valid = gl >= ((lr < 8) ? 2 : 1);
      }
      S[ct][e] = valid ? s : NEGF;
    }
  }
  float mrow[4], invd[4];
#pragma unroll
  for (int e = 0; e < 4; ++e) {
    float mx = S[0][e];
#pragma unroll
    for (int ct = 1; ct < 14; ++ct) mx = fmaxf(mx, S[ct][e]);
    mx = fmaxf(mx, __shfl_xor(mx, 1));
    mx = fmaxf(mx, __shfl_xor(mx, 2));
    mx = fmaxf(mx, __shfl_xor(mx, 4));
    mx = fmaxf(mx, __shfl_xor(mx, 8));
    mrow[e] = mx;
  }
#pragma unroll
  for (int e = 0; e < 4; ++e) {
    float sum = 0.f;
#pragma unroll
    for (int ct = 0; ct < 14; ++ct) {
      float sc = (ct < 8) ? 1.0f : (float)(8 << (ct - 8));
      float ev = sc * __expf(S[ct][e] - mrow[e]);
      S[ct][e] = ev;
      sum += ev;
    }
    sum += __shfl_xor(sum, 1);
    sum += __shfl_xor(sum, 2);
    sum += __shfl_xor(sum, 4);
    sum += __shfl_xor(sum, 8);
    invd[e] = 1.0f / sum;
  }
#pragma unroll
  for (int ct = 0; ct < 14; ++ct) {
#pragma unroll
    for (int e = 0; e < 4; ++e) {
      int rr = w * 16 + lg * 4 + e;
      Pl[rr * 232 + ct * 16 + lr] = f2bf(S[ct][e] * invd[e]);
    }
  }
  __syncthreads();

  f32x4 O[4];
#pragma unroll
  for (int c2 = 0; c2 < 4; ++c2) O[c2] = zero4();
#pragma unroll
  for (int kc = 0; kc < 7; ++kc) {
    bf16x8 pa = ld_bf8(&Pl[(w * 16 + lr) * 232 + kc * 32 + lg * 8]);
    int kk = kc * 32 + lg * 8;
#pragma unroll
    for (int c2 = 0; c2 < 4; ++c2) {
      int d = c2 * 16 + lr;
      const unsigned short* vr;
      if (kk < 128) {
        int t = (g - 1) * 64 + kk;
        int tc = t < 0 ? 0 : t;
        vr = vt + ((size_t)bh * 64 + d) * T_SEQ + tc;
      } else {
        int idx = kk - 128;
        int lvl0 = idx >> 4;
        int j = idx & 15;
        int gl = g >> lvl0;
        int off = 2048 - (2048 >> lvl0);
        int prow = (gl - 2) * 8 + j;
        int prc = prow < 0 ? 0 : prow;
        vr = vtpool + ((size_t)bh * 64 + d) * NPOOL + off + prc;
      }
      O[c2] = mfma16(pa, ld_bf8(vr), O[c2]);
    }
  }
  const int bb = bh >> 4, hh = bh & 15;
#pragma unroll
  for (int c2 = 0; c2 < 4; ++c2) {
    int d = c2 * 16 + lr;
#pragma unroll
    for (int e = 0; e < 4; ++e) {
      int t = g * 64 + w * 16 + lg * 4 + e;
      o[((size_t)bb * T_SEQ + t) * 1024 + hh * 64 + d] = f2bf(O[c2][e]);
    }
  }
}

// ---------------------------------------------------------------------------
extern "C" void kernel_launch(void* const* d_in, const int* in_sizes, int n_in,
                              void* d_out, int out_size, void* d_ws, size_t ws_size,
                              hipStream_t stream) {
  const float* x  = (const float*)d_in[0];
  const float* Wa = (const float*)d_in[1];
  const float* ba = (const float*)d_in[2];
  const float* Wp = (const float*)d_in[3];
  const float* bp = (const float*)d_in[4];
  float* out = (float*)d_out;
  char* ws = (char*)d_ws;
  const size_t MB = 1024 * 1024;

  unsigned short* xb  = (unsigned short*)(ws);             // 64MB (dead after GEMM1)
  unsigned short* qb  = (unsigned short*)(ws + 64 * MB);   // 64MB
  unsigned short* kb  = (unsigned short*)(ws + 128 * MB);  // 64MB
  unsigned short* vb  = (unsigned short*)(ws + 192 * MB);  // 64MB (-> attn out)
  unsigned short* vt  = (unsigned short*)(ws + 256 * MB);  // 64MB
  unsigned short* wat = (unsigned short*)(ws + 320 * MB);  // 6MB
  unsigned short* wpt = (unsigned short*)(ws + 326 * MB);  // 2MB
  unsigned short* kpool  = xb;                             // aliases xb
  unsigned short* vtpool = (unsigned short*)(ws + 32 * MB);// aliases xb

  hipFuncSetAttribute((const void*)gemm256<12, 0>,
                      hipFuncAttributeMaxDynamicSharedMemorySize, 131072);
  hipFuncSetAttribute((const void*)gemm256<4, 1>,
                      hipFuncAttributeMaxDynamicSharedMemorySize, 131072);

  castx_k<<<16384, 256, 0, stream>>>(x, xb);
  transposeW_k<<<dim3(48, 16), 256, 0, stream>>>(Wa, wat, 1024, 3072);
  transposeW_k<<<dim3(16, 16), 256, 0, stream>>>(Wp, wpt, 1024, 1024);
  gemm256<12, 0><<<1536, 512, 131072, stream>>>(xb, wat, ba, qb, kb, vb, nullptr);
  transposeV_k<<<dim3(128, 64), 256, 0, stream>>>(vb, vt);
  poolK_k<<<dim3(32, 64), 256, 0, stream>>>(kb, kpool);
  poolV_k<<<dim3(64, 64), 256, 0, stream>>>(vt, vtpool);
  attn_k<<<dim3(128, 64), 256, 0, stream>>>(qb, kb, kpool, vt, vtpool, vb);
  gemm256<4, 1><<<512, 512, 131072, stream>>>(vb, wpt, bp, nullptr, nullptr, nullptr, out);
}

// Round 3
// 641.405 us; speedup vs baseline: 1.1271x; 1.0036x over previous
//
#include <hip/hip_runtime.h>
#include <hip/hip_bf16.h>
#include <stdint.h>

// ---------------------------------------------------------------------------
// FMA-style hierarchical causal attention, MI355X (gfx950)
// B=4 T=8192 C=1024 H=16 D=64 M=64 P=8 L=6  -> BH=64, fine blocks nb0=128
// R3: GEMMs -> K-half ring pipeline (4x32KB slots), per-phase read/MFMA
//     overlap, counted vmcnt(4), raw s_barrier, setprio. T1+T2+T4+T5.
// ---------------------------------------------------------------------------

typedef float  f32x4  __attribute__((ext_vector_type(4)));
typedef __bf16 bf16x8 __attribute__((ext_vector_type(8)));
typedef unsigned short ushort8 __attribute__((ext_vector_type(8)));

__device__ __forceinline__ unsigned short f2bf(float f) {
  union { float f; unsigned u; } v; v.f = f;
  unsigned r = v.u + 0x7fffu + ((v.u >> 16) & 1u);
  return (unsigned short)(r >> 16);
}
__device__ __forceinline__ float bf2f(unsigned short s) {
  union { unsigned u; float f; } v; v.u = ((unsigned)s) << 16;
  return v.f;
}
__device__ __forceinline__ bf16x8 ld_bf8(const unsigned short* p) {
  return __builtin_bit_cast(bf16x8, *(const ushort8*)p);
}
__device__ __forceinline__ f32x4 mfma16(bf16x8 a, bf16x8 b, f32x4 c) {
  return __builtin_amdgcn_mfma_f32_16x16x32_bf16(a, b, c, 0, 0, 0);
}
__device__ __forceinline__ f32x4 zero4() {
  f32x4 z; z[0] = 0.f; z[1] = 0.f; z[2] = 0.f; z[3] = 0.f; return z;
}
__device__ __forceinline__ void gload16(const void* g, void* lds) {
  __builtin_amdgcn_global_load_lds(
      (const __attribute__((address_space(1))) void*)(uintptr_t)g,
      (__attribute__((address_space(3))) void*)(unsigned int)(uintptr_t)lds,
      16, 0, 0);
}

#define T_SEQ 8192
#define NPOOL 2016   // 1024+512+256+128+64+32 pooled rows per bh

// --------------------------- cast x -> bf16 --------------------------------
__global__ __launch_bounds__(256) void castx_k(const float* __restrict__ x,
                                               unsigned short* __restrict__ xb) {
  size_t i = ((size_t)blockIdx.x * 256 + threadIdx.x) * 8;
  float4 a = *(const float4*)(x + i);
  float4 b = *(const float4*)(x + i + 4);
  ushort8 o;
  o[0] = f2bf(a.x); o[1] = f2bf(a.y); o[2] = f2bf(a.z); o[3] = f2bf(a.w);
  o[4] = f2bf(b.x); o[5] = f2bf(b.y); o[6] = f2bf(b.z); o[7] = f2bf(b.w);
  *(ushort8*)(xb + i) = o;
}

// ---------------- transpose W [R][C] f32 -> [C][R] bf16 --------------------
__global__ __launch_bounds__(256) void transposeW_k(const float* __restrict__ w,
                                                    unsigned short* __restrict__ wt,
                                                    int R, int C) {
  __shared__ float tile[64 * 65];
  int cc = blockIdx.x, rc = blockIdx.y;
  int tid = threadIdx.x;
#pragma unroll
  for (int p = 0; p < 4; ++p) {
    int ci = p * 256 + tid;
    int r = ci >> 4, q4 = ci & 15;
    float4 v = *(const float4*)(w + (size_t)(rc * 64 + r) * C + cc * 64 + q4 * 4);
    tile[r * 65 + q4 * 4 + 0] = v.x;
    tile[r * 65 + q4 * 4 + 1] = v.y;
    tile[r * 65 + q4 * 4 + 2] = v.z;
    tile[r * 65 + q4 * 4 + 3] = v.w;
  }
  __syncthreads();
#pragma unroll
  for (int p = 0; p < 2; ++p) {
    int orow = p * 32 + (tid >> 3), tg = tid & 7;
    ushort8 ov;
#pragma unroll
    for (int i = 0; i < 8; ++i) ov[i] = f2bf(tile[(tg * 8 + i) * 65 + orow]);
    *(ushort8*)(wt + (size_t)(cc * 64 + orow) * R + rc * 64 + tg * 8) = ov;
  }
}

// ---------------------------------------------------------------------------
// 256x256 GEMM, K=1024, K-half ring pipeline.
// A [M][1024] bf16 rm, Bt [N][1024] bf16 (= B^T). 512 thr = 8 waves (2x4),
// per-wave out 128x64 (acc[8][4]). LDS 128KB = 4 ring slots x 32KB; slot s
// holds K-half S (tile S>>1, kh S&1): A 256x32 + B 256x32, slot = S&3.
// Per tile: 4 phases; phase = {reads for NEXT phase; one 4-load half-stage;
// counted vmcnt(4); s_barrier; setprio(1); 16 MFMA; setprio(0)}.
// Swizzle: phys seg p holds logical seg p^((row>>1)&3) -> 2-way banks (free).
// Hazards: slot written in phase X was last read >=3 barriers earlier; slot
// read in phase X is covered by an all-threads vmcnt(4)+barrier. vmcnt never
// 0 in steady loop (tail only).
// EPI 0: scatter qkv + bias -> [bh][t][d]; EPI 1: f32 out[m][n] + bias.
// ---------------------------------------------------------------------------
template<int NTILE_N, int EPI>
__global__ __launch_bounds__(512, 2) void gemm256(
    const unsigned short* __restrict__ A, const unsigned short* __restrict__ Bt,
    const float* __restrict__ bias,
    unsigned short* __restrict__ o0, unsigned short* __restrict__ o1,
    unsigned short* __restrict__ o2, float* __restrict__ fout) {
  extern __shared__ __align__(16) char smem[];
  const int K = 1024;
  const int nwg = 128 * NTILE_N;
  const int q = nwg >> 3;
  const int wg = ((int)blockIdx.x & 7) * q + ((int)blockIdx.x >> 3);  // XCD swizzle
  const int tm = wg & 127, tn = wg >> 7;
  const int tid = threadIdx.x;
  const int wid = tid >> 6, lane = tid & 63;
  const int wm = wid >> 2, wn = wid & 3;
  const int lr = lane & 15, lg = lane >> 4;

  // ---- staging addressing: thread covers rows (pass*128 + tid>>2), seg ----
  const int srow = tid >> 2;                       // 0..127
  const int sseg = (tid & 3) ^ ((tid >> 3) & 3);   // pre-swizzled source seg
  const unsigned short* aSrc = A + (size_t)(tm * 256 + srow) * K + sseg * 8;
  const unsigned short* bSrc = Bt + (size_t)(tn * 256 + srow) * K + sseg * 8;
  const unsigned ldsT = (unsigned)tid * 16;

  // ---- fragment read addressing ----
  const unsigned psel = (unsigned)((lg ^ ((lr >> 1) & 3)) * 16);
  const unsigned aBase = (unsigned)(wm * 8192 + lr * 64) + psel;
  const unsigned bBase = (unsigned)(16384 + wn * 4096 + lr * 64) + psel;

  f32x4 acc[8][4];
#pragma unroll
  for (int i = 0; i < 8; ++i)
#pragma unroll
    for (int j = 0; j < 4; ++j) acc[i][j] = zero4();

  bf16x8 rA0[4], rA1[4], rB0[4], rB1[4];

  auto SB = [&]() {
    __builtin_amdgcn_sched_barrier(0);
    __builtin_amdgcn_s_barrier();
    __builtin_amdgcn_sched_barrier(0);
  };
  auto VM4 = [&]() {
    __builtin_amdgcn_sched_barrier(0);
    asm volatile("s_waitcnt vmcnt(4)" ::: "memory");
    __builtin_amdgcn_sched_barrier(0);
  };
  auto VM0 = [&]() {
    __builtin_amdgcn_sched_barrier(0);
    asm volatile("s_waitcnt vmcnt(0)" ::: "memory");
    __builtin_amdgcn_sched_barrier(0);
  };
  // stage one K-half (A 256x32 + B 256x32 = 4 loads) into ring slot slotB
  auto stage2 = [&](int coffShorts, unsigned slotB) {
#pragma unroll
    for (int pass = 0; pass < 2; ++pass) {
      gload16(aSrc + (size_t)pass * 128 * K + coffShorts,
              smem + slotB + pass * 8192 + ldsT);
      gload16(bSrc + (size_t)pass * 128 * K + coffShorts,
              smem + slotB + 16384 + pass * 8192 + ldsT);
    }
  };
  auto rdA = [&](bf16x8 (&dst)[4], unsigned slotB, int ih) {
    const char* p = smem + slotB + aBase + ih * 4096;
#pragma unroll
    for (int ii = 0; ii < 4; ++ii)
      dst[ii] = ld_bf8((const unsigned short*)(p + ii * 1024));
  };
  auto rdB = [&](bf16x8 (&dst)[4], unsigned slotB) {
    const char* p = smem + slotB + bBase;
#pragma unroll
    for (int j = 0; j < 4; ++j)
      dst[j] = ld_bf8((const unsigned short*)(p + j * 1024));
  };
  auto cluster = [&](int rb, bf16x8 (&a)[4], bf16x8 (&b)[4]) {
    __builtin_amdgcn_s_setprio(1);
#pragma unroll
    for (int ii = 0; ii < 4; ++ii)
#pragma unroll
      for (int j = 0; j < 4; ++j)
        acc[rb + ii][j] = mfma16(a[ii], b[j], acc[rb + ii][j]);
    __builtin_amdgcn_s_setprio(0);
  };

  // one steady tile t (t < 15): slots s0B/s1B hold tile t kh0/kh1;
  // sn0B/sn1B receive tile t+1 kh0/kh1.
  auto steady = [&](int t, unsigned s0B, unsigned s1B, unsigned sn0B,
                    unsigned sn1B) {
    const int cn = (t + 1) * 64;
    // P0: MFMA(ih0,kh0) | reads A(ih1,kh0) | stage t+1 kh0
    stage2(cn, sn0B);
    rdA(rA1, s0B, 1);
    VM4();  // drains S(2t+1): kh1 slot ready for P1 reads
    SB();
    cluster(0, rA0, rB0);
    // P1: MFMA(ih1,kh0) | reads A(ih0,kh1)+B(kh1) | stage t+1 kh1
    stage2(cn + 32, sn1B);
    rdA(rA0, s1B, 0);
    rdB(rB1, s1B);
    SB();
    cluster(4, rA1, rB0);
    // P2: MFMA(ih0,kh1) | reads A(ih1,kh1)
    rdA(rA1, s1B, 1);
    VM4();  // drains S(2t+2): next-tile kh0 slot ready for P3 reads
    SB();
    cluster(0, rA0, rB1);
    // P3: MFMA(ih1,kh1) | reads A/B of tile t+1 kh0
    rdA(rA0, sn0B, 0);
    rdB(rB0, sn0B);
    SB();
    cluster(4, rA1, rB1);
  };

  // ---- prologue: stage tile0 kh0/kh1, wait kh0, preload P0 frags ----
  stage2(0, 0u);
  stage2(32, 32768u);
  VM4();
  SB();
  rdA(rA0, 0u, 0);
  rdB(rB0, 0u);

  // ---- steady loop: 15 tiles, slots cycle with period 2 ----
  for (int tp = 0; tp < 7; ++tp) {
    steady(2 * tp, 0u, 32768u, 65536u, 98304u);
    steady(2 * tp + 1, 65536u, 98304u, 0u, 32768u);
  }
  steady(14, 0u, 32768u, 65536u, 98304u);

  // ---- tail tile 15 (slots 2,3): no stages, no next reads ----
  rdA(rA1, 65536u, 1);
  VM0();  // S31 (kh1) landed
  SB();
  cluster(0, rA0, rB0);
  rdA(rA0, 98304u, 0);
  rdB(rB1, 98304u);
  SB();
  cluster(4, rA1, rB0);
  rdA(rA1, 98304u, 1);
  SB();
  cluster(0, rA0, rB1);
  SB();
  cluster(4, rA1, rB1);

  // ---- epilogue ----
  const int mBase = tm * 256 + wm * 128 + lg * 4;
  const int nBase = tn * 256 + wn * 64 + lr;
  if (EPI == 0) {
#pragma unroll
    for (int j = 0; j < 4; ++j) {
      int n = nBase + j * 16;
      float bv = bias[n];
      int region = n >> 10, nn = n & 1023, hh = nn >> 6, d = nn & 63;
      unsigned short* dst = region == 0 ? o0 : (region == 1 ? o1 : o2);
#pragma unroll
      for (int i = 0; i < 8; ++i) {
#pragma unroll
        for (int e = 0; e < 4; ++e) {
          int m = mBase + i * 16 + e;
          int bb = m >> 13, tq = m & 8191;
          dst[(((size_t)(bb * 16 + hh)) * T_SEQ + tq) * 64 + d] = f2bf(acc[i][j][e] + bv);
        }
      }
    }
  } else {
#pragma unroll
    for (int j = 0; j < 4; ++j) {
      int n = nBase + j * 16;
      float bv = bias[n];
#pragma unroll
      for (int i = 0; i < 8; ++i) {
#pragma unroll
        for (int e = 0; e < 4; ++e) {
          int m = mBase + i * 16 + e;
          fout[(size_t)m * 1024 + n] = acc[i][j][e] + bv;
        }
      }
    }
  }
}

// ---------------- transpose v [bh][t][d] -> Vt [bh][d][t] ------------------
__global__ __launch_bounds__(256) void transposeV_k(const unsigned short* __restrict__ v,
                                                    unsigned short* __restrict__ vt) {
  __shared__ float tile[64 * 65];
  int tc = blockIdx.x, bh = blockIdx.y;
  int tid = threadIdx.x;
#pragma unroll
  for (int p = 0; p < 2; ++p) {
    int r = p * 32 + (tid >> 3), cg = tid & 7;
    ushort8 u = *(const ushort8*)(v + ((size_t)bh * T_SEQ + (size_t)tc * 64 + r) * 64 + cg * 8);
#pragma unroll
    for (int i = 0; i < 8; ++i) tile[r * 65 + cg * 8 + i] = bf2f(u[i]);
  }
  __syncthreads();
#pragma unroll
  for (int p = 0; p < 2; ++p) {
    int dd = p * 32 + (tid >> 3), tg = tid & 7;
    ushort8 ov;
#pragma unroll
    for (int i = 0; i < 8; ++i) ov[i] = f2bf(tile[(tg * 8 + i) * 65 + dd]);
    *(ushort8*)(vt + ((size_t)bh * 64 + dd) * T_SEQ + (size_t)tc * 64 + tg * 8) = ov;
  }
}

// ---------------- pool K: k [bh][t][d] -> kpool [bh][2016][d] --------------
__global__ __launch_bounds__(256) void poolK_k(const unsigned short* __restrict__ kin,
                                               unsigned short* __restrict__ kpool) {
  __shared__ float buf[64 * 65];
  int chunk = blockIdx.x, bh = blockIdx.y;
  int tid = threadIdx.x;
  int cg = tid & 7, orow = tid >> 3;
  float s[8];
#pragma unroll
  for (int i = 0; i < 8; ++i) s[i] = 0.f;
  const unsigned short* base =
      kin + ((size_t)bh * T_SEQ + chunk * 256 + orow * 8) * 64 + cg * 8;
#pragma unroll
  for (int rr = 0; rr < 8; ++rr) {
    ushort8 v = *(const ushort8*)(base + (size_t)rr * 64);
#pragma unroll
    for (int i = 0; i < 8; ++i) s[i] += bf2f(v[i]);
  }
  unsigned short* kp = kpool + (size_t)bh * NPOOL * 64;
  {
    ushort8 ov;
#pragma unroll
    for (int i = 0; i < 8; ++i) {
      s[i] *= 0.125f;
      ov[i] = f2bf(s[i]);
      buf[orow * 65 + cg * 8 + i] = s[i];
    }
    *(ushort8*)(kp + ((size_t)(chunk * 32 + orow)) * 64 + cg * 8) = ov;
  }
  __syncthreads();
  int srcR = 0, dstR = 32;
#pragma unroll
  for (int lvl = 2; lvl <= 6; ++lvl) {
    int rows = 32 >> (lvl - 1);
    int off = 2048 - (2048 >> (lvl - 1));
    if (orow < rows) {
      ushort8 ov;
      float tv[8];
#pragma unroll
      for (int i = 0; i < 8; ++i) {
        tv[i] = 0.5f * (buf[(srcR + 2 * orow) * 65 + cg * 8 + i] +
                        buf[(srcR + 2 * orow + 1) * 65 + cg * 8 + i]);
        ov[i] = f2bf(tv[i]);
      }
      *(ushort8*)(kp + ((size_t)(off + chunk * rows + orow)) * 64 + cg * 8) = ov;
#pragma unroll
      for (int i = 0; i < 8; ++i) buf[(dstR + orow) * 65 + cg * 8 + i] = tv[i];
    }
    __syncthreads();
    srcR = dstR;
    dstR += rows;
  }
}

// ---------------- pool V (transposed space): Vt -> Vtpool ------------------
__global__ __launch_bounds__(256) void poolV_k(const unsigned short* __restrict__ vt,
                                               unsigned short* __restrict__ vtpool) {
  __shared__ float buf[1024 + 512 + 256 + 128 + 64];
  int d = blockIdx.x, bh = blockIdx.y;
  int tid = threadIdx.x;
  const unsigned short* src = vt + ((size_t)bh * 64 + d) * T_SEQ;
  unsigned short* dst = vtpool + ((size_t)bh * 64 + d) * NPOOL;
#pragma unroll
  for (int p = 0; p < 4; ++p) {
    int oi = p * 256 + tid;
    ushort8 v = *(const ushort8*)(src + (size_t)oi * 8);
    float s = 0.f;
#pragma unroll
    for (int i = 0; i < 8; ++i) s += bf2f(v[i]);
    s *= 0.125f;
    dst[oi] = f2bf(s);
    buf[oi] = s;
  }
  __syncthreads();
  float* b1 = buf; float* b2 = buf + 1024;
#pragma unroll
  for (int p = 0; p < 2; ++p) {
    int oi = p * 256 + tid;
    float s = 0.5f * (b1[2 * oi] + b1[2 * oi + 1]);
    dst[1024 + oi] = f2bf(s);
    b2[oi] = s;
  }
  __syncthreads();
  float* b3 = b2 + 512;
  {
    float s = 0.5f * (b2[2 * tid] + b2[2 * tid + 1]);
    dst[1536 + tid] = f2bf(s);
    b3[tid] = s;
  }
  __syncthreads();
  float* b4 = b3 + 256;
  if (tid < 128) {
    float s = 0.5f * (b3[2 * tid] + b3[2 * tid + 1]);
    dst[1792 + tid] = f2bf(s);
    b4[tid] = s;
  }
  __syncthreads();
  float* b5 = b4 + 128;
  if (tid < 64) {
    float s = 0.5f * (b4[2 * tid] + b4[2 * tid + 1]);
    dst[1920 + tid] = f2bf(s);
    b5[tid] = s;
  }
  __syncthreads();
  if (tid < 32) {
    float s = 0.5f * (b5[2 * tid] + b5[2 * tid + 1]);
    dst[1984 + tid] = f2bf(s);
  }
}

// ---------------- fused hierarchical attention -----------------------------
__global__ __launch_bounds__(256) void attn_k(const unsigned short* __restrict__ q,
                                              const unsigned short* __restrict__ k,
                                              const unsigned short* __restrict__ kpool,
                                              const unsigned short* __restrict__ vt,
                                              const unsigned short* __restrict__ vtpool,
                                              unsigned short* __restrict__ o) {
  const int g = blockIdx.x;
  const int bh = blockIdx.y;
  const int tid = threadIdx.x;
  const int w = tid >> 6, l = tid & 63;
  const int lr = l & 15, lg = l >> 4;
  __shared__ unsigned short Pl[64 * 232];

  const size_t qoff = ((size_t)bh * T_SEQ + (size_t)g * 64 + w * 16 + lr) * 64 + lg * 8;
  bf16x8 aq0 = ld_bf8(q + qoff);
  bf16x8 aq1 = ld_bf8(q + qoff + 32);

  f32x4 S[14];
#pragma unroll
  for (int ct = 0; ct < 14; ++ct) S[ct] = zero4();

#pragma unroll
  for (int ct = 0; ct < 8; ++ct) {
    int t = (g - 1) * 64 + ct * 16 + lr;
    int tc = t < 0 ? 0 : t;
    const unsigned short* kr = k + ((size_t)bh * T_SEQ + tc) * 64 + lg * 8;
    S[ct] = mfma16(aq0, ld_bf8(kr), S[ct]);
    S[ct] = mfma16(aq1, ld_bf8(kr + 32), S[ct]);
  }
#pragma unroll
  for (int lvl = 1; lvl <= 6; ++lvl) {
    int ct = 7 + lvl;
    int gl = g >> (lvl - 1);
    int off = 2048 - (2048 >> (lvl - 1));
    int prow = (gl - 2) * 8 + lr;
    int prc = prow < 0 ? 0 : prow;
    const unsigned short* kr = kpool + ((size_t)bh * NPOOL + off + prc) * 64 + lg * 8;
    S[ct] = mfma16(aq0, ld_bf8(kr), S[ct]);
    S[ct] = mfma16(aq1, ld_bf8(kr + 32), S[ct]);
  }

  const float NEGF = -1e30f;
#pragma unroll
  for (int ct = 0; ct < 14; ++ct) {
#pragma unroll
    for (int e = 0; e < 4; ++e) {
      int rr = w * 16 + lg * 4 + e;
      float s = S[ct][e] * 0.125f;
      bool valid;
      if (ct < 8) {
        int cc = ct * 16 + lr;
        valid = (cc > rr) && (cc <= rr + 64) && ((g >= 1) || (cc >= 64));
      } else {
        int lvl = ct - 7;
        int gl = g >> (lvl - 1);
        valid = gl >= ((lr < 8) ? 2 : 1);
      }
      S[ct][e] = valid ? s : NEGF;
    }
  }
  float mrow[4], invd[4];
#pragma unroll
  for (int e = 0; e < 4; ++e) {
    float mx = S[0][e];
#pragma unroll
    for (int ct = 1; ct < 14; ++ct) mx = fmaxf(mx, S[ct][e]);
    mx = fmaxf(mx, __shfl_xor(mx, 1));
    mx = fmaxf(mx, __shfl_xor(mx, 2));
    mx = fmaxf(mx, __shfl_xor(mx, 4));
    mx = fmaxf(mx, __shfl_xor(mx, 8));
    mrow[e] = mx;
  }
#pragma unroll
  for (int e = 0; e < 4; ++e) {
    float sum = 0.f;
#pragma unroll
    for (int ct = 0; ct < 14; ++ct) {
      float sc = (ct < 8) ? 1.0f : (float)(8 << (ct - 8));
      float ev = sc * __expf(S[ct][e] - mrow[e]);
      S[ct][e] = ev;
      sum += ev;
    }
    sum += __shfl_xor(sum, 1);
    sum += __shfl_xor(sum, 2);
    sum += __shfl_xor(sum, 4);
    sum += __shfl_xor(sum, 8);
    invd[e] = 1.0f / sum;
  }
#pragma unroll
  for (int ct = 0; ct < 14; ++ct) {
#pragma unroll
    for (int e = 0; e < 4; ++e) {
      int rr = w * 16 + lg * 4 + e;
      Pl[rr * 232 + ct * 16 + lr] = f2bf(S[ct][e] * invd[e]);
    }
  }
  __syncthreads();

  f32x4 O[4];
#pragma unroll
  for (int c2 = 0; c2 < 4; ++c2) O[c2] = zero4();
#pragma unroll
  for (int kc = 0; kc < 7; ++kc) {
    bf16x8 pa = ld_bf8(&Pl[(w * 16 + lr) * 232 + kc * 32 + lg * 8]);
    int kk = kc * 32 + lg * 8;
#pragma unroll
    for (int c2 = 0; c2 < 4; ++c2) {
      int d = c2 * 16 + lr;
      const unsigned short* vr;
      if (kk < 128) {
        int t = (g - 1) * 64 + kk;
        int tc = t < 0 ? 0 : t;
        vr = vt + ((size_t)bh * 64 + d) * T_SEQ + tc;
      } else {
        int idx = kk - 128;
        int lvl0 = idx >> 4;
        int j = idx & 15;
        int gl = g >> lvl0;
        int off = 2048 - (2048 >> lvl0);
        int prow = (gl - 2) * 8 + j;
        int prc = prow < 0 ? 0 : prow;
        vr = vtpool + ((size_t)bh * 64 + d) * NPOOL + off + prc;
      }
      O[c2] = mfma16(pa, ld_bf8(vr), O[c2]);
    }
  }
  const int bb = bh >> 4, hh = bh & 15;
#pragma unroll
  for (int c2 = 0; c2 < 4; ++c2) {
    int d = c2 * 16 + lr;
#pragma unroll
    for (int e = 0; e < 4; ++e) {
      int t = g * 64 + w * 16 + lg * 4 + e;
      o[((size_t)bb * T_SEQ + t) * 1024 + hh * 64 + d] = f2bf(O[c2][e]);
    }
  }
}

// ---------------------------------------------------------------------------
extern "C" void kernel_launch(void* const* d_in, const int* in_sizes, int n_in,
                              void* d_out, int out_size, void* d_ws, size_t ws_size,
                              hipStream_t stream) {
  const float* x  = (const float*)d_in[0];
  const float* Wa = (const float*)d_in[1];
  const float* ba = (const float*)d_in[2];
  const float* Wp = (const float*)d_in[3];
  const float* bp = (const float*)d_in[4];
  float* out = (float*)d_out;
  char* ws = (char*)d_ws;
  const size_t MB = 1024 * 1024;

  unsigned short* xb  = (unsigned short*)(ws);             // 64MB (dead after GEMM1)
  unsigned short* qb  = (unsigned short*)(ws + 64 * MB);   // 64MB
  unsigned short* kb  = (unsigned short*)(ws + 128 * MB);  // 64MB
  unsigned short* vb  = (unsigned short*)(ws + 192 * MB);  // 64MB (-> attn out)
  unsigned short* vt  = (unsigned short*)(ws + 256 * MB);  // 64MB
  unsigned short* wat = (unsigned short*)(ws + 320 * MB);  // 6MB
  unsigned short* wpt = (unsigned short*)(ws + 326 * MB);  // 2MB
  unsigned short* kpool  = xb;                             // aliases xb
  unsigned short* vtpool = (unsigned short*)(ws + 32 * MB);// aliases xb

  hipFuncSetAttribute((const void*)gemm256<12, 0>,
                      hipFuncAttributeMaxDynamicSharedMemorySize, 131072);
  hipFuncSetAttribute((const void*)gemm256<4, 1>,
                      hipFuncAttributeMaxDynamicSharedMemorySize, 131072);

  castx_k<<<16384, 256, 0, stream>>>(x, xb);
  transposeW_k<<<dim3(48, 16), 256, 0, stream>>>(Wa, wat, 1024, 3072);
  transposeW_k<<<dim3(16, 16), 256, 0, stream>>>(Wp, wpt, 1024, 1024);
  gemm256<12, 0><<<1536, 512, 131072, stream>>>(xb, wat, ba, qb, kb, vb, nullptr);
  transposeV_k<<<dim3(128, 64), 256, 0, stream>>>(vb, vt);
  poolK_k<<<dim3(32, 64), 256, 0, stream>>>(kb, kpool);
  poolV_k<<<dim3(64, 64), 256, 0, stream>>>(vt, vtpool);
  attn_k<<<dim3(128, 64), 256, 0, stream>>>(qb, kb, kpool, vt, vtpool, vb);
  gemm256<4, 1><<<512, 512, 131072, stream>>>(vb, wpt, bp, nullptr, nullptr, nullptr, out);
}